// Round 1
// baseline (711.299 us; speedup 1.0000x reference)
//
#include <hip/hip_runtime.h>
#include <stdint.h>

#define HW_   65536
#define B_    4
#define C_    256
#define P_    256
#define TH_   0.8f
#define EPS_  1e-5f

// ---------------------------------------------------------------------------
// key: (float bits of thresholded edge) << 32 | (65535 - i)
// unsigned-descending order == (value desc, index asc) == jax.lax.top_k order.
// All keys distinct (index embedded) -> exact selection.
// ---------------------------------------------------------------------------
__device__ __forceinline__ uint64_t make_key(const float* __restrict__ edge, int b, int i) {
    float v = edge[b * HW_ + i];
    if (v < TH_) v = 0.0f;
    uint32_t fb = __float_as_uint(v);           // v >= 0 -> bits order == value order
    return ((uint64_t)fb << 32) | (uint32_t)(65535 - i);
}

__global__ __launch_bounds__(1024) void topk_kernel(const float* __restrict__ edge,
                                                    int* __restrict__ idx_out) {
    const int b = blockIdx.x;
    const int tid = threadIdx.x;
    __shared__ unsigned int hist[256];
    __shared__ int s_digit;
    __shared__ unsigned int s_above;
    __shared__ unsigned int s_cnt;
    __shared__ uint64_t skeys[256];

    // --- radix select: find the key of rank 256 (1-indexed, descending) ---
    uint64_t prefix = 0, mask = 0;
    int k = P_;
    for (int shift = 56; shift >= 0; shift -= 8) {
        if (tid < 256) hist[tid] = 0;
        __syncthreads();
        for (int s = 0; s < HW_ / 1024; ++s) {
            int i = tid + s * 1024;
            uint64_t key = make_key(edge, b, i);
            if ((key & mask) == prefix)
                atomicAdd(&hist[(unsigned)(key >> shift) & 255u], 1u);
        }
        __syncthreads();
        if (tid == 0) {
            unsigned int c = 0;
            int d = 255;
            for (; d > 0; --d) {
                unsigned int h = hist[d];
                if (c + h >= (unsigned)k) break;
                c += h;
            }
            s_digit = d;
            s_above = c;
        }
        __syncthreads();
        k -= (int)s_above;
        prefix |= ((uint64_t)(unsigned)s_digit) << shift;
        mask   |= (255ull << shift);
        __syncthreads();   // hist reused next round
    }
    // prefix == exact key of the 256th-largest element

    // --- collect the 256 keys >= kth key ---
    if (tid == 0) s_cnt = 0;
    __syncthreads();
    for (int s = 0; s < HW_ / 1024; ++s) {
        int i = tid + s * 1024;
        uint64_t key = make_key(edge, b, i);
        if (key >= prefix) {
            unsigned int pos = atomicAdd(&s_cnt, 1u);
            if (pos < 256u) skeys[pos] = key;
        }
    }
    __syncthreads();

    // --- bitonic sort 256 keys, descending ---
    for (int kk = 2; kk <= 256; kk <<= 1) {
        for (int j = kk >> 1; j > 0; j >>= 1) {
            if (tid < 256) {
                int ixj = tid ^ j;
                if (ixj > tid) {
                    uint64_t a = skeys[tid], c2 = skeys[ixj];
                    bool desc = ((tid & kk) == 0);
                    if (desc ? (a < c2) : (a > c2)) { skeys[tid] = c2; skeys[ixj] = a; }
                }
            }
            __syncthreads();
        }
    }
    if (tid < 256) idx_out[b * P_ + tid] = 65535 - (int)(skeys[tid] & 0xFFFFFFFFull);
}

// ---------------------------------------------------------------------------
// gather: feat[b][n][d] = x[b][d][idx[b][n]]   (B,P,C) row-major
// ---------------------------------------------------------------------------
__global__ __launch_bounds__(256) void gather_kernel(const float* __restrict__ x,
                                                     const int* __restrict__ idx,
                                                     float* __restrict__ feat) {
    const int bn = blockIdx.x;           // b*P_ + n
    const int d = threadIdx.x;           // 0..255
    const int b = bn >> 8;
    const int hw = idx[bn];              // broadcast (scalar) load
    feat[(size_t)bn * C_ + d] = x[((size_t)(b * C_ + d)) * HW_ + hw];
}

// ---------------------------------------------------------------------------
// stage 1: z = relu(bn_adj(w_adj @ feat)) + feat      (per batch, 256x256x256)
// 64x64 tile / block, 256 threads, 4x4 microtile
// ---------------------------------------------------------------------------
__global__ __launch_bounds__(256) void mm1_kernel(const float* __restrict__ w_adj,
                                                  const float* __restrict__ feat,
                                                  const float* __restrict__ g,
                                                  const float* __restrict__ bb,
                                                  const float* __restrict__ m,
                                                  const float* __restrict__ vv,
                                                  float* __restrict__ z) {
    __shared__ __align__(16) float a_s[64][68];
    __shared__ __align__(16) float b_s[64][68];
    const int b = blockIdx.y;
    const int i0 = (blockIdx.x >> 2) * 64;
    const int d0 = (blockIdx.x & 3) * 64;
    const int tid = threadIdx.x;
    const int tx = tid & 15, ty = tid >> 4;
    const float* fb = feat + (size_t)b * P_ * C_;

    float acc[4][4] = {};
    for (int k0 = 0; k0 < 256; k0 += 64) {
        for (int l = tid; l < 4096; l += 256) {
            int r = l >> 6, c = l & 63;
            a_s[r][c] = w_adj[(i0 + r) * 256 + (k0 + c)];
            b_s[r][c] = fb[(size_t)(k0 + r) * 256 + (d0 + c)];
        }
        __syncthreads();
        #pragma unroll
        for (int kk = 0; kk < 64; kk += 4) {
            float4 a4[4], b4[4];
            #pragma unroll
            for (int r = 0; r < 4; ++r) a4[r] = *(const float4*)&a_s[ty * 4 + r][kk];
            #pragma unroll
            for (int j = 0; j < 4; ++j) b4[j] = *(const float4*)&b_s[kk + j][tx * 4];
            #pragma unroll
            for (int r = 0; r < 4; ++r) {
                const float4 av = a4[r];
                const float aj0 = av.x, aj1 = av.y, aj2 = av.z, aj3 = av.w;
                acc[r][0] = fmaf(aj0, b4[0].x, acc[r][0]);
                acc[r][1] = fmaf(aj0, b4[0].y, acc[r][1]);
                acc[r][2] = fmaf(aj0, b4[0].z, acc[r][2]);
                acc[r][3] = fmaf(aj0, b4[0].w, acc[r][3]);
                acc[r][0] = fmaf(aj1, b4[1].x, acc[r][0]);
                acc[r][1] = fmaf(aj1, b4[1].y, acc[r][1]);
                acc[r][2] = fmaf(aj1, b4[1].z, acc[r][2]);
                acc[r][3] = fmaf(aj1, b4[1].w, acc[r][3]);
                acc[r][0] = fmaf(aj2, b4[2].x, acc[r][0]);
                acc[r][1] = fmaf(aj2, b4[2].y, acc[r][1]);
                acc[r][2] = fmaf(aj2, b4[2].z, acc[r][2]);
                acc[r][3] = fmaf(aj2, b4[2].w, acc[r][3]);
                acc[r][0] = fmaf(aj3, b4[3].x, acc[r][0]);
                acc[r][1] = fmaf(aj3, b4[3].y, acc[r][1]);
                acc[r][2] = fmaf(aj3, b4[3].z, acc[r][2]);
                acc[r][3] = fmaf(aj3, b4[3].w, acc[r][3]);
            }
        }
        __syncthreads();
    }
    // epilogue: BN(row i) + relu + residual
    #pragma unroll
    for (int r = 0; r < 4; ++r) {
        const int i = i0 + ty * 4 + r;
        const float inv = g[i] / sqrtf(vv[i] + EPS_);
        const float beta = bb[i] - m[i] * inv;
        const int d = d0 + tx * 4;
        float4 res = *(const float4*)&fb[(size_t)i * 256 + d];
        float4 o;
        o.x = fmaxf(acc[r][0] * inv + beta, 0.0f) + res.x;
        o.y = fmaxf(acc[r][1] * inv + beta, 0.0f) + res.y;
        o.z = fmaxf(acc[r][2] * inv + beta, 0.0f) + res.z;
        o.w = fmaxf(acc[r][3] * inv + beta, 0.0f) + res.w;
        *(float4*)&z[((size_t)b * P_ + i) * C_ + d] = o;
    }
}

// ---------------------------------------------------------------------------
// stage 2 + scatter: out[b][c][idx[b][p]] = relu(bn_wg(sum_d w_wg[c][d]*z[b][p][d]))
// ---------------------------------------------------------------------------
__global__ __launch_bounds__(256) void mm2_kernel(const float* __restrict__ w_wg,
                                                  const float* __restrict__ z,
                                                  const int* __restrict__ idx,
                                                  const float* __restrict__ g,
                                                  const float* __restrict__ bb,
                                                  const float* __restrict__ m,
                                                  const float* __restrict__ vv,
                                                  float* __restrict__ out) {
    __shared__ __align__(16) float a_s[64][68];
    __shared__ __align__(16) float bt_s[64][68];   // bt_s[d][p] = z[p][d]
    const int b = blockIdx.y;
    const int c0 = (blockIdx.x >> 2) * 64;
    const int p0 = (blockIdx.x & 3) * 64;
    const int tid = threadIdx.x;
    const int tx = tid & 15, ty = tid >> 4;
    const float* zb = z + (size_t)b * P_ * C_;

    float acc[4][4] = {};
    for (int k0 = 0; k0 < 256; k0 += 64) {
        for (int l = tid; l < 4096; l += 256) {
            int r = l >> 6, c = l & 63;
            a_s[r][c] = w_wg[(c0 + r) * 256 + (k0 + c)];
            // coalesced global read, transposed LDS write
            bt_s[c][r] = zb[(size_t)(p0 + r) * 256 + (k0 + c)];
        }
        __syncthreads();
        #pragma unroll
        for (int kk = 0; kk < 64; kk += 4) {
            float4 a4[4], b4[4];
            #pragma unroll
            for (int r = 0; r < 4; ++r) a4[r] = *(const float4*)&a_s[ty * 4 + r][kk];
            #pragma unroll
            for (int j = 0; j < 4; ++j) b4[j] = *(const float4*)&bt_s[kk + j][tx * 4];
            #pragma unroll
            for (int r = 0; r < 4; ++r) {
                const float4 av = a4[r];
                const float aj0 = av.x, aj1 = av.y, aj2 = av.z, aj3 = av.w;
                acc[r][0] = fmaf(aj0, b4[0].x, acc[r][0]);
                acc[r][1] = fmaf(aj0, b4[0].y, acc[r][1]);
                acc[r][2] = fmaf(aj0, b4[0].z, acc[r][2]);
                acc[r][3] = fmaf(aj0, b4[0].w, acc[r][3]);
                acc[r][0] = fmaf(aj1, b4[1].x, acc[r][0]);
                acc[r][1] = fmaf(aj1, b4[1].y, acc[r][1]);
                acc[r][2] = fmaf(aj1, b4[1].z, acc[r][2]);
                acc[r][3] = fmaf(aj1, b4[1].w, acc[r][3]);
                acc[r][0] = fmaf(aj2, b4[2].x, acc[r][0]);
                acc[r][1] = fmaf(aj2, b4[2].y, acc[r][1]);
                acc[r][2] = fmaf(aj2, b4[2].z, acc[r][2]);
                acc[r][3] = fmaf(aj2, b4[2].w, acc[r][3]);
                acc[r][0] = fmaf(aj3, b4[3].x, acc[r][0]);
                acc[r][1] = fmaf(aj3, b4[3].y, acc[r][1]);
                acc[r][2] = fmaf(aj3, b4[3].z, acc[r][2]);
                acc[r][3] = fmaf(aj3, b4[3].w, acc[r][3]);
            }
        }
        __syncthreads();
    }
    // epilogue: BN(row c) + relu, scattered store into out
    int pidx[4];
    #pragma unroll
    for (int cc = 0; cc < 4; ++cc) pidx[cc] = idx[b * P_ + p0 + tx * 4 + cc];
    #pragma unroll
    for (int r = 0; r < 4; ++r) {
        const int c = c0 + ty * 4 + r;
        const float inv = g[c] / sqrtf(vv[c] + EPS_);
        const float beta = bb[c] - m[c] * inv;
        float* orow = out + ((size_t)(b * C_ + c)) * HW_;
        #pragma unroll
        for (int cc = 0; cc < 4; ++cc) {
            orow[pidx[cc]] = fmaxf(acc[r][cc] * inv + beta, 0.0f);
        }
    }
}

// ---------------------------------------------------------------------------
extern "C" void kernel_launch(void* const* d_in, const int* in_sizes, int n_in,
                              void* d_out, int out_size, void* d_ws, size_t ws_size,
                              hipStream_t stream) {
    const float* x     = (const float*)d_in[0];
    const float* edge  = (const float*)d_in[1];
    const float* w_adj = (const float*)d_in[2];
    const float* g_a   = (const float*)d_in[3];
    const float* b_a   = (const float*)d_in[4];
    const float* m_a   = (const float*)d_in[5];
    const float* v_a   = (const float*)d_in[6];
    const float* w_wg  = (const float*)d_in[7];
    const float* g_w   = (const float*)d_in[8];
    const float* b_w   = (const float*)d_in[9];
    const float* m_w   = (const float*)d_in[10];
    const float* v_w   = (const float*)d_in[11];
    float* out = (float*)d_out;

    // workspace layout
    char* ws = (char*)d_ws;
    int*   idx  = (int*)ws;                                  // B*P ints      (4 KB)
    float* feat = (float*)(ws + 4096);                       // B*P*C floats  (1 MB)
    float* z    = (float*)(ws + 4096 + (size_t)B_ * P_ * C_ * 4); // B*P*C floats

    // 1. bulk copy out = x (512 MB of HBM traffic — the structural floor)
    hipMemcpyAsync(out, x, (size_t)B_ * C_ * HW_ * sizeof(float),
                   hipMemcpyDeviceToDevice, stream);

    // 2. exact top-256 per batch (jax.lax.top_k order)
    topk_kernel<<<B_, 1024, 0, stream>>>(edge, idx);

    // 3. gather feat (B,P,C)
    gather_kernel<<<B_ * P_, 256, 0, stream>>>(x, idx, feat);

    // 4. stage 1 GCN
    mm1_kernel<<<dim3(16, B_), 256, 0, stream>>>(w_adj, feat, g_a, b_a, m_a, v_a, z);

    // 5. stage 2 GCN + scatter into out (after the copy, stream-ordered)
    mm2_kernel<<<dim3(16, B_), 256, 0, stream>>>(w_wg, z, idx, g_w, b_w, m_w, v_w, out);
}

// Round 2
// 615.792 us; speedup vs baseline: 1.1551x; 1.1551x over previous
//
#include <hip/hip_runtime.h>
#include <stdint.h>

#define HW_   65536
#define B_    4
#define C_    256
#define P_    256
#define TH_   0.8f
#define EPS_  1e-5f

#define CHUNK_  4096          // elements per phase-1 block
#define NCHUNK_ (HW_ / CHUNK_) // 16 chunks per batch
#define NCAND_  (NCHUNK_ * P_) // 4096 candidates per batch in phase 2

// ---------------------------------------------------------------------------
// key: (float bits of thresholded edge) << 32 | (65535 - i)
// unsigned-descending == (value desc, index asc) == jax.lax.top_k order.
// Keys are distinct (index embedded) -> exact, deterministic selection.
// ---------------------------------------------------------------------------
__device__ __forceinline__ uint64_t make_key(float v, int i) {
    if (v < TH_) v = 0.0f;
    return ((uint64_t)__float_as_uint(v) << 32) | (uint32_t)(65535 - i);
}

// phase 1: each block exact-sorts a 4096-chunk, emits its top 256 (sorted desc)
__global__ __launch_bounds__(512) void topk_local_kernel(const float* __restrict__ edge,
                                                         uint64_t* __restrict__ cand) {
    __shared__ uint64_t sk[CHUNK_];
    const int b = blockIdx.y;
    const int chunk = blockIdx.x;
    const int tid = threadIdx.x;
    const int base = chunk * CHUNK_;
    for (int t = tid; t < CHUNK_; t += 512) {
        const int i = base + t;
        sk[t] = make_key(edge[b * HW_ + i], i);
    }
    __syncthreads();
    for (int k = 2; k <= CHUNK_; k <<= 1) {
        for (int j = k >> 1; j > 0; j >>= 1) {
            for (int t = tid; t < CHUNK_ / 2; t += 512) {
                const int i = 2 * t - (t & (j - 1));   // index with j-bit clear
                const int ixj = i + j;
                const uint64_t a = sk[i], c = sk[ixj];
                const bool desc = ((i & k) == 0);
                if (desc ? (a < c) : (a > c)) { sk[i] = c; sk[ixj] = a; }
            }
            __syncthreads();
        }
    }
    if (tid < 256) cand[(b * NCHUNK_ + chunk) * P_ + tid] = sk[tid];
}

// phase 2: one block per batch, exact-sorts the 4096 candidates, emits top 256
__global__ __launch_bounds__(1024) void topk_merge_kernel(const uint64_t* __restrict__ cand,
                                                          int* __restrict__ idx_out) {
    __shared__ uint64_t sk[NCAND_];
    const int b = blockIdx.x;
    const int tid = threadIdx.x;
    for (int t = tid; t < NCAND_; t += 1024) sk[t] = cand[b * NCAND_ + t];
    __syncthreads();
    for (int k = 2; k <= NCAND_; k <<= 1) {
        for (int j = k >> 1; j > 0; j >>= 1) {
            for (int t = tid; t < NCAND_ / 2; t += 1024) {
                const int i = 2 * t - (t & (j - 1));
                const int ixj = i + j;
                const uint64_t a = sk[i], c = sk[ixj];
                const bool desc = ((i & k) == 0);
                if (desc ? (a < c) : (a > c)) { sk[i] = c; sk[ixj] = a; }
            }
            __syncthreads();
        }
    }
    if (tid < 256) idx_out[b * P_ + tid] = 65535 - (int)(sk[tid] & 0xFFFFFFFFull);
}

// ---------------------------------------------------------------------------
// bulk copy out = x : 512 MB HBM traffic, the structural floor (~81 us @6.3TB/s)
// ---------------------------------------------------------------------------
__global__ __launch_bounds__(256) void copy_kernel(const float4* __restrict__ src,
                                                   float4* __restrict__ dst, int n4) {
    int i = blockIdx.x * 256 + threadIdx.x;
    const int stride = gridDim.x * 256;
    for (; i < n4; i += stride) dst[i] = src[i];
}

// ---------------------------------------------------------------------------
// gather: feat[b][n][d] = x[b][d][idx[b][n]]   (B,P,C) row-major
// ---------------------------------------------------------------------------
__global__ __launch_bounds__(256) void gather_kernel(const float* __restrict__ x,
                                                     const int* __restrict__ idx,
                                                     float* __restrict__ feat) {
    const int bn = blockIdx.x;           // b*P_ + n
    const int d = threadIdx.x;           // 0..255
    const int b = bn >> 8;
    const int hw = idx[bn];              // broadcast (scalar) load
    feat[(size_t)bn * C_ + d] = x[((size_t)(b * C_ + d)) * HW_ + hw];
}

// ---------------------------------------------------------------------------
// stage 1: z = relu(bn_adj(w_adj @ feat)) + feat      (per batch, 256x256x256)
// 64x64 tile / block, 256 threads, 4x4 microtile
// ---------------------------------------------------------------------------
__global__ __launch_bounds__(256) void mm1_kernel(const float* __restrict__ w_adj,
                                                  const float* __restrict__ feat,
                                                  const float* __restrict__ g,
                                                  const float* __restrict__ bb,
                                                  const float* __restrict__ m,
                                                  const float* __restrict__ vv,
                                                  float* __restrict__ z) {
    __shared__ __align__(16) float a_s[64][68];
    __shared__ __align__(16) float b_s[64][68];
    const int b = blockIdx.y;
    const int i0 = (blockIdx.x >> 2) * 64;
    const int d0 = (blockIdx.x & 3) * 64;
    const int tid = threadIdx.x;
    const int tx = tid & 15, ty = tid >> 4;
    const float* fb = feat + (size_t)b * P_ * C_;

    float acc[4][4] = {};
    for (int k0 = 0; k0 < 256; k0 += 64) {
        for (int l = tid; l < 4096; l += 256) {
            int r = l >> 6, c = l & 63;
            a_s[r][c] = w_adj[(i0 + r) * 256 + (k0 + c)];
            b_s[r][c] = fb[(size_t)(k0 + r) * 256 + (d0 + c)];
        }
        __syncthreads();
        #pragma unroll
        for (int kk = 0; kk < 64; kk += 4) {
            float4 a4[4], b4[4];
            #pragma unroll
            for (int r = 0; r < 4; ++r) a4[r] = *(const float4*)&a_s[ty * 4 + r][kk];
            #pragma unroll
            for (int j = 0; j < 4; ++j) b4[j] = *(const float4*)&b_s[kk + j][tx * 4];
            #pragma unroll
            for (int r = 0; r < 4; ++r) {
                const float4 av = a4[r];
                const float aj0 = av.x, aj1 = av.y, aj2 = av.z, aj3 = av.w;
                acc[r][0] = fmaf(aj0, b4[0].x, acc[r][0]);
                acc[r][1] = fmaf(aj0, b4[0].y, acc[r][1]);
                acc[r][2] = fmaf(aj0, b4[0].z, acc[r][2]);
                acc[r][3] = fmaf(aj0, b4[0].w, acc[r][3]);
                acc[r][0] = fmaf(aj1, b4[1].x, acc[r][0]);
                acc[r][1] = fmaf(aj1, b4[1].y, acc[r][1]);
                acc[r][2] = fmaf(aj1, b4[1].z, acc[r][2]);
                acc[r][3] = fmaf(aj1, b4[1].w, acc[r][3]);
                acc[r][0] = fmaf(aj2, b4[2].x, acc[r][0]);
                acc[r][1] = fmaf(aj2, b4[2].y, acc[r][1]);
                acc[r][2] = fmaf(aj2, b4[2].z, acc[r][2]);
                acc[r][3] = fmaf(aj2, b4[2].w, acc[r][3]);
                acc[r][0] = fmaf(aj3, b4[3].x, acc[r][0]);
                acc[r][1] = fmaf(aj3, b4[3].y, acc[r][1]);
                acc[r][2] = fmaf(aj3, b4[3].z, acc[r][2]);
                acc[r][3] = fmaf(aj3, b4[3].w, acc[r][3]);
            }
        }
        __syncthreads();
    }
    #pragma unroll
    for (int r = 0; r < 4; ++r) {
        const int i = i0 + ty * 4 + r;
        const float inv = g[i] / sqrtf(vv[i] + EPS_);
        const float beta = bb[i] - m[i] * inv;
        const int d = d0 + tx * 4;
        float4 res = *(const float4*)&fb[(size_t)i * 256 + d];
        float4 o;
        o.x = fmaxf(acc[r][0] * inv + beta, 0.0f) + res.x;
        o.y = fmaxf(acc[r][1] * inv + beta, 0.0f) + res.y;
        o.z = fmaxf(acc[r][2] * inv + beta, 0.0f) + res.z;
        o.w = fmaxf(acc[r][3] * inv + beta, 0.0f) + res.w;
        *(float4*)&z[((size_t)b * P_ + i) * C_ + d] = o;
    }
}

// ---------------------------------------------------------------------------
// stage 2 + scatter: out[b][c][idx[b][p]] = relu(bn_wg(sum_d w_wg[c][d]*z[b][p][d]))
// ---------------------------------------------------------------------------
__global__ __launch_bounds__(256) void mm2_kernel(const float* __restrict__ w_wg,
                                                  const float* __restrict__ z,
                                                  const int* __restrict__ idx,
                                                  const float* __restrict__ g,
                                                  const float* __restrict__ bb,
                                                  const float* __restrict__ m,
                                                  const float* __restrict__ vv,
                                                  float* __restrict__ out) {
    __shared__ __align__(16) float a_s[64][68];
    __shared__ __align__(16) float bt_s[64][68];   // bt_s[d][p] = z[p][d]
    const int b = blockIdx.y;
    const int c0 = (blockIdx.x >> 2) * 64;
    const int p0 = (blockIdx.x & 3) * 64;
    const int tid = threadIdx.x;
    const int tx = tid & 15, ty = tid >> 4;
    const float* zb = z + (size_t)b * P_ * C_;

    float acc[4][4] = {};
    for (int k0 = 0; k0 < 256; k0 += 64) {
        for (int l = tid; l < 4096; l += 256) {
            int r = l >> 6, c = l & 63;
            a_s[r][c] = w_wg[(c0 + r) * 256 + (k0 + c)];
            bt_s[c][r] = zb[(size_t)(p0 + r) * 256 + (k0 + c)];
        }
        __syncthreads();
        #pragma unroll
        for (int kk = 0; kk < 64; kk += 4) {
            float4 a4[4], b4[4];
            #pragma unroll
            for (int r = 0; r < 4; ++r) a4[r] = *(const float4*)&a_s[ty * 4 + r][kk];
            #pragma unroll
            for (int j = 0; j < 4; ++j) b4[j] = *(const float4*)&bt_s[kk + j][tx * 4];
            #pragma unroll
            for (int r = 0; r < 4; ++r) {
                const float4 av = a4[r];
                const float aj0 = av.x, aj1 = av.y, aj2 = av.z, aj3 = av.w;
                acc[r][0] = fmaf(aj0, b4[0].x, acc[r][0]);
                acc[r][1] = fmaf(aj0, b4[0].y, acc[r][1]);
                acc[r][2] = fmaf(aj0, b4[0].z, acc[r][2]);
                acc[r][3] = fmaf(aj0, b4[0].w, acc[r][3]);
                acc[r][0] = fmaf(aj1, b4[1].x, acc[r][0]);
                acc[r][1] = fmaf(aj1, b4[1].y, acc[r][1]);
                acc[r][2] = fmaf(aj1, b4[1].z, acc[r][2]);
                acc[r][3] = fmaf(aj1, b4[1].w, acc[r][3]);
                acc[r][0] = fmaf(aj2, b4[2].x, acc[r][0]);
                acc[r][1] = fmaf(aj2, b4[2].y, acc[r][1]);
                acc[r][2] = fmaf(aj2, b4[2].z, acc[r][2]);
                acc[r][3] = fmaf(aj2, b4[2].w, acc[r][3]);
                acc[r][0] = fmaf(aj3, b4[3].x, acc[r][0]);
                acc[r][1] = fmaf(aj3, b4[3].y, acc[r][1]);
                acc[r][2] = fmaf(aj3, b4[3].z, acc[r][2]);
                acc[r][3] = fmaf(aj3, b4[3].w, acc[r][3]);
            }
        }
        __syncthreads();
    }
    int pidx[4];
    #pragma unroll
    for (int cc = 0; cc < 4; ++cc) pidx[cc] = idx[b * P_ + p0 + tx * 4 + cc];
    #pragma unroll
    for (int r = 0; r < 4; ++r) {
        const int c = c0 + ty * 4 + r;
        const float inv = g[c] / sqrtf(vv[c] + EPS_);
        const float beta = bb[c] - m[c] * inv;
        float* orow = out + ((size_t)(b * C_ + c)) * HW_;
        #pragma unroll
        for (int cc = 0; cc < 4; ++cc) {
            orow[pidx[cc]] = fmaxf(acc[r][cc] * inv + beta, 0.0f);
        }
    }
}

// ---------------------------------------------------------------------------
extern "C" void kernel_launch(void* const* d_in, const int* in_sizes, int n_in,
                              void* d_out, int out_size, void* d_ws, size_t ws_size,
                              hipStream_t stream) {
    const float* x     = (const float*)d_in[0];
    const float* edge  = (const float*)d_in[1];
    const float* w_adj = (const float*)d_in[2];
    const float* g_a   = (const float*)d_in[3];
    const float* b_a   = (const float*)d_in[4];
    const float* m_a   = (const float*)d_in[5];
    const float* v_a   = (const float*)d_in[6];
    const float* w_wg  = (const float*)d_in[7];
    const float* g_w   = (const float*)d_in[8];
    const float* b_w   = (const float*)d_in[9];
    const float* m_w   = (const float*)d_in[10];
    const float* v_w   = (const float*)d_in[11];
    float* out = (float*)d_out;

    // workspace layout
    char* ws = (char*)d_ws;
    int*      idx  = (int*)ws;                                       // 4 KB
    uint64_t* cand = (uint64_t*)(ws + 4096);                         // B*4096*8 = 128 KB
    float*    feat = (float*)(ws + 4096 + (size_t)B_ * NCAND_ * 8);  // 1 MB
    float*    z    = feat + (size_t)B_ * P_ * C_;                    // 1 MB

    // 1. bulk copy out = x (512 MB HBM traffic — structural floor)
    copy_kernel<<<4096, 256, 0, stream>>>((const float4*)x, (float4*)out,
                                          (int)((size_t)B_ * C_ * HW_ / 4));

    // 2. exact top-256 per batch (jax.lax.top_k order): local sort + merge
    topk_local_kernel<<<dim3(NCHUNK_, B_), 512, 0, stream>>>(edge, cand);
    topk_merge_kernel<<<B_, 1024, 0, stream>>>(cand, idx);

    // 3. gather feat (B,P,C)
    gather_kernel<<<B_ * P_, 256, 0, stream>>>(x, idx, feat);

    // 4. stage 1 GCN
    mm1_kernel<<<dim3(16, B_), 256, 0, stream>>>(w_adj, feat, g_a, b_a, m_a, v_a, z);

    // 5. stage 2 GCN + scatter into out
    mm2_kernel<<<dim3(16, B_), 256, 0, stream>>>(w_wg, z, idx, g_w, b_w, m_w, v_w, out);
}